// Round 12
// baseline (494.103 us; speedup 1.0000x reference)
//
#include <hip/hip_runtime.h>

#define Bn 4096
#define NF 20
#define NEMB 16
#define HIDN 512
#define KE 16
#define GIN 320
#define NKS 10   // K-steps of 32
#define NBLK 496 // grid size; < 512 capacity (2 blocks/CU) for co-residency margin

typedef __attribute__((ext_vector_type(8))) short short8;
typedef __attribute__((ext_vector_type(4))) float f32x4;

__device__ __forceinline__ unsigned short f2bf(float f) {
  unsigned int u = __builtin_bit_cast(unsigned int, f);
  u += 0x7fff + ((u >> 16) & 1);
  return (unsigned short)(u >> 16);
}
__device__ __forceinline__ float bf2f(unsigned short h) {
  unsigned int u = ((unsigned int)h) << 16;
  return __builtin_bit_cast(float, u);
}

__device__ __forceinline__ void gload_lds16(const unsigned short* g, void* l) {
  __builtin_amdgcn_global_load_lds(
      (const __attribute__((address_space(1))) unsigned int*)g,
      (__attribute__((address_space(3))) unsigned int*)l, 16, 0, 0);
}

__device__ __forceinline__ void vwait(int n) {
  if (n >= 5) asm volatile("s_waitcnt vmcnt(5)" ::: "memory");
  else        asm volatile("s_waitcnt vmcnt(0)" ::: "memory");
  __builtin_amdgcn_sched_barrier(0);
}

// device-scope grid barrier: arrive = 1 RMW/block; poll = plain coherent LOAD
// (round-11 bug: polling with atomicAdd(bar,0) = RMW storm on one LLC line).
__device__ __forceinline__ void gridbar(int* bar, int phase) {
  __threadfence();          // release: flush my writes to coherence point
  __syncthreads();          // all waves of block have fenced
  if (threadIdx.x == 0) {
    __hip_atomic_fetch_add(bar, 1, __ATOMIC_RELEASE, __HIP_MEMORY_SCOPE_AGENT);
    const int tgt = (phase + 1) * NBLK;
    while (__hip_atomic_load(bar, __ATOMIC_RELAXED, __HIP_MEMORY_SCOPE_AGENT) < tgt)
      __builtin_amdgcn_s_sleep(8);
  }
  __syncthreads();
  __threadfence();          // acquire: invalidate stale cached lines
}

__global__ __launch_bounds__(256, 2) void fused_kernel(
    const int* __restrict__ x, const int* __restrict__ sql,
    const float* __restrict__ semb, const float* __restrict__ demb,
    const float* __restrict__ gw1, const float* __restrict__ gb1,
    const float* __restrict__ gw2, const float* __restrict__ gb2,
    const float* __restrict__ ew1, const float* __restrict__ eb1,
    const float* __restrict__ ew2, const float* __restrict__ eb2,
    float* __restrict__ y, int* __restrict__ bar, int* __restrict__ cnt,
    int* __restrict__ list, float* __restrict__ wlist, float* __restrict__ glp,
    unsigned short* __restrict__ SH, unsigned short* __restrict__ SL,
    unsigned short* __restrict__ GWF, unsigned short* __restrict__ EWF,
    unsigned short* __restrict__ XEP) {
  __shared__ __align__(16) char smem[78848];  // union across phases (77 KB)
  const int tid = threadIdx.x, lane = tid & 63, wv = tid >> 6;
  const int bid = blockIdx.x;

  // ================= phase 0: prep (1760 units, grid-stride) ================
  for (int u = bid; u < 1760; u += NBLK) {
    long long t = (long long)u * 256 + tid;
    if (t < 81920) {
      int row = (int)(t / NF), f = (int)(t % NF);
      int idx = sql[row * NF + f];
      const float4* s = (const float4*)(semb + (size_t)idx * NEMB);
      float4 v[4] = {s[0], s[1], s[2], s[3]};
      const float* sf = (const float*)v;
      short8 h0, h1, l0, l1;
#pragma unroll
      for (int i = 0; i < 8; i++) {
        float a = sf[i];
        unsigned short hb = f2bf(a);
        h0[i] = (short)hb; l0[i] = (short)f2bf(a - bf2f(hb));
        a = sf[8 + i];
        hb = f2bf(a);
        h1[i] = (short)hb; l1[i] = (short)f2bf(a - bf2f(hb));
      }
      size_t o = (size_t)row * GIN + f * NEMB;
      *(short8*)(SH + o) = h0; *(short8*)(SH + o + 8) = h1;
      *(short8*)(SL + o) = l0; *(short8*)(SL + o + 8) = l1;
    } else if (t < 81920 + 40960) {
      long long t2 = t - 81920;
      int s = (int)(t2 / 20480), r = (int)(t2 % 20480);
      int ks = r / 2048, r2 = r % 2048, nt = r2 / 64, l = r2 % 64;
      int k0 = ks * 32 + (l >> 4) * 8, n = nt * 16 + (l & 15);
      short8 o;
#pragma unroll
      for (int j = 0; j < 8; j++) {
        float w = gw1[(size_t)(k0 + j) * HIDN + n];
        unsigned short hb = f2bf(w);
        o[j] = (s == 0) ? (short)hb : (short)f2bf(w - bf2f(hb));
      }
      *(short8*)(GWF + ((((size_t)s * NKS + ks) * 32 + nt) * 64 + l) * 8) = o;
    } else {
      long long t2 = t - 122880;
      int e = (int)(t2 / 20480), r = (int)(t2 % 20480);
      int ks = r / 2048, r2 = r % 2048, nt = r2 / 64, l = r2 % 64;
      int k0 = ks * 32 + (l >> 4) * 8, n = nt * 16 + (l & 15);
      const float* W = ew1 + (size_t)e * GIN * HIDN;
      short8 o;
#pragma unroll
      for (int j = 0; j < 8; j++) o[j] = (short)f2bf(W[(size_t)(k0 + j) * HIDN + n]);
      *(short8*)(EWF + ((((size_t)e * NKS + ks) * 32 + nt) * 64 + l) * 8) = o;
    }
  }
  gridbar(bar, 0);

  // ================= phase 1: gate (512 work-blocks) ========================
  {
    unsigned short (*ring)[10240] = (unsigned short(*)[10240])smem;   // 60 KB
    float (*hs)[68] = (float(*)[68])(smem + 61440);                   // 17.4 KB
    for (int b = bid; b < 512; b += NBLK) {
      __syncthreads();  // previous iteration's epilogue done with smem
      const int xcd = b & 7, r_ = b >> 3;
      const int cb = r_ & 7;
      const int band = (8 * xcd + (r_ >> 3)) * 64;
      const int ntg = cb * 4 + wv;

      short8 bh[NKS], bl[NKS];
#pragma unroll
      for (int ks = 0; ks < NKS; ks++) {
        bh[ks] = *(const short8*)(GWF + ((size_t)(ks * 32 + ntg)) * 512 + lane * 8);
        bl[ks] = *(const short8*)(GWF + ((size_t)((NKS + ks) * 32 + ntg)) * 512 + lane * 8);
      }
      const int cl = wv * 16 + (lane & 15);
      const float b1v = gb1[cb * 64 + cl];
      __builtin_amdgcn_sched_barrier(0);

#define GSTG(pi, slot)                                                        \
  {                                                                           \
    _Pragma("unroll") for (int i = 0; i < 5; i++) {                           \
      int c = wv * 5 + i;                                                     \
      int hl = c >= 10, kss = c - hl * 10;                                    \
      const unsigned short* s_ = (hl ? SL : SH) +                             \
          (size_t)(band + (pi) * 16 + (lane & 15)) * GIN + kss * 32 +         \
          (lane >> 4) * 8;                                                    \
      gload_lds16(s_, &ring[slot][c * 512 + lane * 8]);                       \
    }                                                                         \
  }
      GSTG(0, 0) GSTG(1, 1)
      __builtin_amdgcn_sched_barrier(0);

#pragma unroll
      for (int p = 0; p < 4; p++) {
        vwait(p < 3 ? 5 : 0);
        __builtin_amdgcn_s_barrier();
        __builtin_amdgcn_sched_barrier(0);
        if (p + 2 < 4) GSTG(p + 2, (p + 2) % 3)
        __builtin_amdgcn_sched_barrier(0);
        const unsigned short* rb = ring[p % 3];
        f32x4 acc = {};
#pragma unroll
        for (int ks = 0; ks < NKS; ks++) {
          short8 ah = *(const short8*)&rb[ks * 512 + lane * 8];
          short8 al = *(const short8*)&rb[(NKS + ks) * 512 + lane * 8];
          acc = __builtin_amdgcn_mfma_f32_16x16x32_bf16(ah, bh[ks], acc, 0, 0, 0);
          acc = __builtin_amdgcn_mfma_f32_16x16x32_bf16(al, bh[ks], acc, 0, 0, 0);
          acc = __builtin_amdgcn_mfma_f32_16x16x32_bf16(ah, bl[ks], acc, 0, 0, 0);
        }
#pragma unroll
        for (int j = 0; j < 4; j++)
          hs[p * 16 + (lane >> 4) * 4 + j][cl] = fmaxf(acc[j] + b1v, 0.f);
      }
      __syncthreads();

      float (*g2s)[16] = (float(*)[16])smem;  // reuse ring[0]
      ((float4*)g2s)[tid] = ((const float4*)(gw2 + (size_t)cb * 64 * KE))[tid];
      __syncthreads();
#pragma unroll
      for (int it = 0; it < 4; it++) {
        int row = it * 16 + (tid >> 4), q = tid & 15;
        float s = 0.f;
#pragma unroll 8
        for (int c = 0; c < 64; c++) s = fmaf(hs[row][c], g2s[c][q], s);
        glp[((size_t)cb * Bn + band + row) * KE + q] = s;
      }
#undef GSTG
    }
  }
  gridbar(bar, 1);

  // ================= phase 2: gate2 (blocks 0..63) ==========================
  if (bid < 64) {
    float (*part)[64][KE] = (float(*)[64][KE])smem;     // 16 KB
    int* lcnt  = (int*)(smem + 16384);
    int* gbase = (int*)(smem + 16448);
    const int r = tid & 63, g = tid >> 6;
    const int row = bid * 64 + r;
    if (tid < KE) lcnt[tid] = 0;
    float lg[KE];
#pragma unroll
    for (int q = 0; q < KE; q++) lg[q] = 0.f;
#pragma unroll
    for (int s2 = 0; s2 < 2; s2++) {
      const float4* a = (const float4*)(glp + ((size_t)(2 * g + s2) * Bn + row) * KE);
#pragma unroll
      for (int u = 0; u < 4; u++) {
        float4 v = a[u];
        lg[u * 4 + 0] += v.x; lg[u * 4 + 1] += v.y;
        lg[u * 4 + 2] += v.z; lg[u * 4 + 3] += v.w;
      }
    }
#pragma unroll
    for (int q = 0; q < KE; q++) part[g][r][q] = lg[q];
    __syncthreads();
    if (tid < 64) {
#pragma unroll
      for (int q = 0; q < KE; q++)
        lg[q] = part[0][tid][q] + part[1][tid][q] + part[2][tid][q] +
                part[3][tid][q] + gb2[q];
      float m = lg[0];
#pragma unroll
      for (int q = 1; q < KE; q++) m = fmaxf(m, lg[q]);
      float e[KE];
#pragma unroll
      for (int q = 0; q < KE; q++) e[q] = expf(lg[q] - m);
      int i1 = 0; float v1 = e[0];
#pragma unroll
      for (int q = 1; q < KE; q++) if (e[q] > v1) { v1 = e[q]; i1 = q; }
      int i2 = (i1 == 0) ? 1 : 0; float v2 = e[i2];
#pragma unroll
      for (int q = 0; q < KE; q++)
        if (q != i1 && e[q] > v2) { v2 = e[q]; i2 = q; }
      int rowg = bid * 64 + tid;
      int o1 = atomicAdd(&lcnt[i1], 1);
      int o2 = atomicAdd(&lcnt[i2], 1);
      __syncthreads();
      if (tid < KE) gbase[tid] = atomicAdd(&cnt[tid], lcnt[tid]);
      __syncthreads();
      float den = v1 + v2;
      int s1 = gbase[i1] + o1;
      list[i1 * Bn + s1] = rowg; wlist[i1 * Bn + s1] = v1 / den;
      int s2 = gbase[i2] + o2;
      list[i2 * Bn + s2] = rowg; wlist[i2 * Bn + s2] = v2 / den;
    } else {
      __syncthreads();
      __syncthreads();
    }
  }
  gridbar(bar, 2);

  // ================= phase 3: pack + loss (1040 units) ======================
  {
    float (*simp)[KE] = (float(*)[KE])smem;
    float* fimp = (float*)(smem + 1024);
    for (int u = bid; u < 1040; u += NBLK) {
      const int xcd = u & 7, r_ = u >> 3;
      const int k = xcd + 8 * (r_ & 1), jb = r_ >> 1;
      if (jb == 64) {
        if (k != 0) continue;
        const int kk = tid >> 4, g = tid & 15;
        const int n = cnt[kk];
        float s = 0.f;
        for (int j = g; j < n; j += 16) s += wlist[kk * Bn + j];
        simp[kk][g] = s;
        __syncthreads();
        if (tid < KE) {
          float t = 0.f;
          for (int q = 0; q < KE; q++) t += simp[tid][q];
          fimp[tid] = t;
        }
        __syncthreads();
        if (tid == 0) {
          double mi = 0.0, ml = 0.0;
          for (int q = 0; q < KE; q++) { mi += fimp[q]; ml += (double)cnt[q]; }
          mi /= KE; ml /= KE;
          double vi = 0.0, vl = 0.0;
          for (int q = 0; q < KE; q++) {
            double di = fimp[q] - mi; vi += di * di;
            double dl = (double)cnt[q] - ml; vl += dl * dl;
          }
          vi /= KE; vl /= KE;
          y[Bn] = (float)(vi / (mi * mi + 1e-10) + vl / (ml * ml + 1e-10));
        }
        continue;
      }
      const int n = cnt[k];
      if (jb * 64 >= n) continue;
      unsigned short* reg = XEP + (size_t)k * 1310720;
#pragma unroll
      for (int it = 0; it < 5; it++) {
        int tt = it * 256 + tid;
        int i = jb * 64 + tt / NF, f = tt % NF;
        if (i < n) {
          int rid = list[k * Bn + i];
          int idx = x[rid * NF + f];
          const float4* s = (const float4*)(demb + (size_t)idx * NEMB);
          float4 v[4] = {s[0], s[1], s[2], s[3]};
          const float* sf = (const float*)v;
          short8 o0, o1;
#pragma unroll
          for (int e = 0; e < 8; e++) {
            o0[e] = (short)f2bf(sf[e]);
            o1[e] = (short)f2bf(sf[8 + e]);
          }
          int panel = i >> 5, mt = (i >> 4) & 1, lr = i & 15;
          int ks = f >> 1, ko0 = (f & 1) * 2;
          unsigned short* d =
              reg + (size_t)panel * 10240 + ks * 1024 + mt * 512 + ko0 * 128 + lr * 8;
          *(short8*)d = o0;
          *(short8*)(d + 128) = o1;
        }
      }
    }
  }
  gridbar(bar, 3);

  // ================= phase 4: expert (512 work-blocks) ======================
  {
    unsigned short (*ring)[10240] = (unsigned short(*)[10240])smem;   // 60 KB
    float (*pb)[4][32] = (float(*)[4][32])(smem + 61440);             // 8 KB
    for (int b = bid; b < 512; b += NBLK) {
      __syncthreads();
      const int xcd = b & 7, r_ = b >> 3;
      const int k = xcd + 8 * (r_ & 1);
      const int cb = (r_ >> 1) & 3, qz = r_ >> 3;
      const int n = cnt[k];
      const int np = (n + 31) >> 5;
      const int npb = (np > qz) ? ((np - qz + 7) >> 3) : 0;
      if (npb == 0) continue;
      const unsigned short* XEPk = XEP + (size_t)k * 1310720;
      const int kBn = k * Bn;

      float b1v[2], w2v[2];
#pragma unroll
      for (int nt = 0; nt < 2; nt++) {
        int colg = cb * 128 + (wv * 2 + nt) * 16 + (lane & 15);
        b1v[nt] = eb1[(size_t)k * HIDN + colg];
        w2v[nt] = ew2[(size_t)k * HIDN + colg];
      }
      short8 bb[2][NKS];
#pragma unroll
      for (int nt = 0; nt < 2; nt++)
#pragma unroll
        for (int ks = 0; ks < NKS; ks++)
          bb[nt][ks] = *(const short8*)(
              EWF + ((size_t)((k * NKS + ks) * 32 + cb * 8 + wv * 2 + nt)) * 512 +
              lane * 8);
      __builtin_amdgcn_sched_barrier(0);

#define ESTG(pi, slot)                                                        \
  {                                                                           \
    _Pragma("unroll") for (int i = 0; i < 5; i++) {                           \
      int c = wv * 5 + i;                                                     \
      gload_lds16(XEPk + (size_t)(pi) * 10240 + c * 512 + lane * 8,           \
                  &ring[slot][c * 512 + lane * 8]);                           \
    }                                                                         \
  }
      ESTG(qz, 0)
      if (npb > 1) ESTG(qz + 8, 1)
      __builtin_amdgcn_sched_barrier(0);

      for (int p = 0; p < npb; p++) {
        vwait((p + 1 < npb) ? 5 : 0);
        __builtin_amdgcn_s_barrier();
        __builtin_amdgcn_sched_barrier(0);
        if (p + 2 < npb) ESTG(qz + 8 * (p + 2), (p + 2) % 3)
        __builtin_amdgcn_sched_barrier(0);
        const unsigned short* rb = ring[p % 3];
        f32x4 acc[2][2] = {};
#pragma unroll
        for (int ks = 0; ks < NKS; ks++) {
          short8 a0 = *(const short8*)&rb[ks * 1024 + lane * 8];
          short8 a1 = *(const short8*)&rb[ks * 1024 + 512 + lane * 8];
          acc[0][0] = __builtin_amdgcn_mfma_f32_16x16x32_bf16(a0, bb[0][ks], acc[0][0], 0, 0, 0);
          acc[0][1] = __builtin_amdgcn_mfma_f32_16x16x32_bf16(a0, bb[1][ks], acc[0][1], 0, 0, 0);
          acc[1][0] = __builtin_amdgcn_mfma_f32_16x16x32_bf16(a1, bb[0][ks], acc[1][0], 0, 0, 0);
          acc[1][1] = __builtin_amdgcn_mfma_f32_16x16x32_bf16(a1, bb[1][ks], acc[1][1], 0, 0, 0);
        }
        float part[2][4];
#pragma unroll
        for (int mt = 0; mt < 2; mt++)
#pragma unroll
          for (int j = 0; j < 4; j++)
            part[mt][j] = fmaxf(acc[mt][0][j] + b1v[0], 0.f) * w2v[0] +
                          fmaxf(acc[mt][1][j] + b1v[1], 0.f) * w2v[1];
#pragma unroll
        for (int off = 8; off >= 1; off >>= 1)
#pragma unroll
          for (int mt = 0; mt < 2; mt++)
#pragma unroll
            for (int j = 0; j < 4; j++)
              part[mt][j] += __shfl_xor(part[mt][j], off);
        if ((lane & 15) == 0) {
#pragma unroll
          for (int mt = 0; mt < 2; mt++)
#pragma unroll
            for (int j = 0; j < 4; j++)
              pb[p][wv][mt * 16 + (lane >> 4) * 4 + j] = part[mt][j];
        }
      }
      __syncthreads();

      const float e2 = (cb == 0) ? eb2[k] : 0.f;
      for (int t = tid; t < npb * 32; t += 256) {
        int pp = t >> 5, r = t & 31;
        int i = (qz + 8 * pp) * 32 + r;
        if (i < n) {
          float v = pb[pp][0][r] + pb[pp][1][r] + pb[pp][2][r] + pb[pp][3][r];
          atomicAdd(&y[list[kBn + i]], wlist[kBn + i] * (v + e2));
        }
      }
#undef ESTG
    }
  }
}

extern "C" void kernel_launch(void* const* d_in, const int* in_sizes, int n_in,
                              void* d_out, int out_size, void* d_ws, size_t ws_size,
                              hipStream_t stream) {
  const int* x      = (const int*)d_in[0];
  const int* sql    = (const int*)d_in[1];
  const float* semb = (const float*)d_in[2];
  const float* demb = (const float*)d_in[3];
  const float* gw1  = (const float*)d_in[4];
  const float* gb1  = (const float*)d_in[5];
  const float* gw2  = (const float*)d_in[6];
  const float* gb2  = (const float*)d_in[7];
  const float* ew1  = (const float*)d_in[8];
  const float* eb1  = (const float*)d_in[9];
  const float* ew2  = (const float*)d_in[10];
  const float* eb2  = (const float*)d_in[11];
  float* y = (float*)d_out;

  char* ws = (char*)d_ws;
  int* cnt            = (int*)(ws);                        // 64 B
  int* bar            = (int*)(ws + 64);                   // grid barrier
  int* list           = (int*)(ws + 4096);                 // 256 KB
  float* wlist        = (float*)(ws + 266240);             // 256 KB
  float* glp          = (float*)(ws + 528384);             // 2 MB (8 slices)
  unsigned short* SH  = (unsigned short*)(ws + 5246976);   // 2.62 MB
  unsigned short* SL  = (unsigned short*)(ws + 7868416);   // 2.62 MB
  unsigned short* GWF = (unsigned short*)(ws + 10489856);  // 655 KB
  unsigned short* EWF = (unsigned short*)(ws + 11145216);  // 5.24 MB
  unsigned short* XEP = (unsigned short*)(ws + 16777216);  // 42 MB packed A

  hipMemsetAsync(ws, 0, 4096, stream);                    // cnt + barrier
  hipMemsetAsync(d_out, 0, (Bn + 1) * sizeof(float), stream);  // y + loss slot
  fused_kernel<<<NBLK, 256, 0, stream>>>(x, sql, semb, demb, gw1, gb1, gw2, gb2,
                                         ew1, eb1, ew2, eb2, y, bar, cnt, list,
                                         wlist, glp, SH, SL, GWF, EWF, XEP);
}

// Round 13
// 62.929 us; speedup vs baseline: 7.8518x; 7.8518x over previous
//
#include <hip/hip_runtime.h>

#define Bn 4096
#define NF 20
#define NEMB 16
#define HIDN 512
#define KE 16
#define GIN 320
#define NKS 10   // K-steps of 32

typedef __attribute__((ext_vector_type(8))) short short8;
typedef __attribute__((ext_vector_type(4))) float f32x4;

__device__ __forceinline__ unsigned short f2bf(float f) {
  unsigned int u = __builtin_bit_cast(unsigned int, f);
  u += 0x7fff + ((u >> 16) & 1);
  return (unsigned short)(u >> 16);
}
__device__ __forceinline__ float bf2f(unsigned short h) {
  unsigned int u = ((unsigned int)h) << 16;
  return __builtin_bit_cast(float, u);
}

__device__ __forceinline__ void gload_lds16(const unsigned short* g, void* l) {
  __builtin_amdgcn_global_load_lds(
      (const __attribute__((address_space(1))) unsigned int*)g,
      (__attribute__((address_space(3))) unsigned int*)l, 16, 0, 0);
}

__device__ __forceinline__ void vwait(int n) {
  if (n >= 5) asm volatile("s_waitcnt vmcnt(5)" ::: "memory");
  else        asm volatile("s_waitcnt vmcnt(0)" ::: "memory");
  __builtin_amdgcn_sched_barrier(0);
}

// ---------------- prep: SH/SL gather-convert, GWF/EWF fragment weights ------
__global__ __launch_bounds__(256) void prep_kernel(
    const int* __restrict__ sql, const float* __restrict__ semb,
    const float* __restrict__ gw1, const float* __restrict__ ew1,
    unsigned short* __restrict__ SH, unsigned short* __restrict__ SL,
    unsigned short* __restrict__ GWF, unsigned short* __restrict__ EWF,
    float* __restrict__ y, int* __restrict__ cnt) {
  long long t = (long long)blockIdx.x * 256 + threadIdx.x;
  if (t < 81920) {
    int row = (int)(t / NF), f = (int)(t % NF);
    int idx = sql[row * NF + f];
    const float4* s = (const float4*)(semb + (size_t)idx * NEMB);
    float4 v[4] = {s[0], s[1], s[2], s[3]};
    const float* sf = (const float*)v;
    short8 h0, h1, l0, l1;
#pragma unroll
    for (int i = 0; i < 8; i++) {
      float a = sf[i];
      unsigned short hb = f2bf(a);
      h0[i] = (short)hb; l0[i] = (short)f2bf(a - bf2f(hb));
      a = sf[8 + i];
      hb = f2bf(a);
      h1[i] = (short)hb; l1[i] = (short)f2bf(a - bf2f(hb));
    }
    size_t o = (size_t)row * GIN + f * NEMB;
    *(short8*)(SH + o) = h0; *(short8*)(SH + o + 8) = h1;
    *(short8*)(SL + o) = l0; *(short8*)(SL + o + 8) = l1;
    return;
  }
  t -= 81920;
  if (t < 40960) {
    int s = (int)(t / 20480), r = (int)(t % 20480);
    int ks = r / 2048, r2 = r % 2048, nt = r2 / 64, l = r2 % 64;
    int k0 = ks * 32 + (l >> 4) * 8, n = nt * 16 + (l & 15);
    short8 o;
#pragma unroll
    for (int j = 0; j < 8; j++) {
      float w = gw1[(size_t)(k0 + j) * HIDN + n];
      unsigned short hb = f2bf(w);
      o[j] = (s == 0) ? (short)hb : (short)f2bf(w - bf2f(hb));
    }
    *(short8*)(GWF + ((((size_t)s * NKS + ks) * 32 + nt) * 64 + l) * 8) = o;
    return;
  }
  t -= 40960;
  if (t < 327680) {
    int e = (int)(t / 20480), r = (int)(t % 20480);
    int ks = r / 2048, r2 = r % 2048, nt = r2 / 64, l = r2 % 64;
    int k0 = ks * 32 + (l >> 4) * 8, n = nt * 16 + (l & 15);
    const float* W = ew1 + (size_t)e * GIN * HIDN;
    short8 o;
#pragma unroll
    for (int j = 0; j < 8; j++) o[j] = (short)f2bf(W[(size_t)(k0 + j) * HIDN + n]);
    *(short8*)(EWF + ((((size_t)e * NKS + ks) * 32 + nt) * 64 + l) * 8) = o;
    return;
  }
  t -= 327680;
  if (t < Bn + 1) y[t] = 0.f;
  else if (t < Bn + 1 + KE) cnt[t - (Bn + 1)] = 0;
}

// ---------------- gate: split-bf16 MFMA, ring-3, XCD-pinned bands -----------
// 1D grid 512: xcd=bid&7 owns bands 8*xcd..8*xcd+7 (A slice L2-resident).
__global__ __launch_bounds__(256, 2) void gate_kernel(
    const unsigned short* __restrict__ SH, const unsigned short* __restrict__ SL,
    const unsigned short* __restrict__ GWF, const float* __restrict__ gb1,
    const float* __restrict__ gw2, float* __restrict__ glp) {
  __shared__ __align__(16) unsigned short ring[3][10240];  // 60 KB
  __shared__ float hs[64][68];                             // 17.4 KB
  const int tid = threadIdx.x, lane = tid & 63, wv = tid >> 6;
  const int bid = blockIdx.x;
  const int xcd = bid & 7, r_ = bid >> 3;
  const int cb = r_ & 7;
  const int band = (8 * xcd + (r_ >> 3)) * 64;
  const int ntg = cb * 4 + wv;

  short8 bh[NKS], bl[NKS];
#pragma unroll
  for (int ks = 0; ks < NKS; ks++) {
    bh[ks] = *(const short8*)(GWF + ((size_t)(ks * 32 + ntg)) * 512 + lane * 8);
    bl[ks] = *(const short8*)(GWF + ((size_t)((NKS + ks) * 32 + ntg)) * 512 + lane * 8);
  }
  const int cl = wv * 16 + (lane & 15);
  const float b1v = gb1[cb * 64 + cl];
  __builtin_amdgcn_sched_barrier(0);

#define GSTG(pi, slot)                                                        \
  {                                                                           \
    _Pragma("unroll") for (int i = 0; i < 5; i++) {                           \
      int c = wv * 5 + i;                                                     \
      int hl = c >= 10, kss = c - hl * 10;                                    \
      const unsigned short* s_ = (hl ? SL : SH) +                             \
          (size_t)(band + (pi) * 16 + (lane & 15)) * GIN + kss * 32 +         \
          (lane >> 4) * 8;                                                    \
      gload_lds16(s_, &ring[slot][c * 512 + lane * 8]);                       \
    }                                                                         \
  }

  GSTG(0, 0) GSTG(1, 1)
  __builtin_amdgcn_sched_barrier(0);

#pragma unroll
  for (int p = 0; p < 4; p++) {
    vwait(p < 3 ? 5 : 0);
    __builtin_amdgcn_s_barrier();
    __builtin_amdgcn_sched_barrier(0);
    if (p + 2 < 4) GSTG(p + 2, (p + 2) % 3)
    __builtin_amdgcn_sched_barrier(0);
    const unsigned short* rb = ring[p % 3];
    f32x4 acc = {};
#pragma unroll
    for (int ks = 0; ks < NKS; ks++) {
      short8 ah = *(const short8*)&rb[ks * 512 + lane * 8];
      short8 al = *(const short8*)&rb[(NKS + ks) * 512 + lane * 8];
      acc = __builtin_amdgcn_mfma_f32_16x16x32_bf16(ah, bh[ks], acc, 0, 0, 0);
      acc = __builtin_amdgcn_mfma_f32_16x16x32_bf16(al, bh[ks], acc, 0, 0, 0);
      acc = __builtin_amdgcn_mfma_f32_16x16x32_bf16(ah, bl[ks], acc, 0, 0, 0);
    }
#pragma unroll
    for (int j = 0; j < 4; j++)
      hs[p * 16 + (lane >> 4) * 4 + j][cl] = fmaxf(acc[j] + b1v, 0.f);
  }
  __syncthreads();

  float (*g2s)[16] = (float(*)[16])&ring[0][0];
  ((float4*)g2s)[tid] = ((const float4*)(gw2 + (size_t)cb * 64 * KE))[tid];
  __syncthreads();
#pragma unroll
  for (int it = 0; it < 4; it++) {
    int row = it * 16 + (tid >> 4), q = tid & 15;
    float s = 0.f;
#pragma unroll 8
    for (int c = 0; c < 64; c++) s = fmaf(hs[row][c], g2s[c][q], s);
    glp[((size_t)cb * Bn + band + row) * KE + q] = s;
  }
#undef GSTG
}

// ---------------- gate2 + pack fused: softmax/top-2/bucket, then XEP pack ---
// grid 64 x 256thr. After slot allocation each block packs its own 64 rows'
// fragment panels for both selected experts (128 entries x 20 fields).
__global__ __launch_bounds__(256) void gate2pack_kernel(
    const float* __restrict__ glp, const float* __restrict__ gb2,
    const int* __restrict__ x, const float* __restrict__ demb,
    int* __restrict__ cnt, int* __restrict__ list, float* __restrict__ wlist,
    unsigned short* __restrict__ XEP) {
  __shared__ float part[4][64][KE];  // 16 KB
  __shared__ int lcnt[KE];
  __shared__ int gbase[KE];
  __shared__ int selk[64][2];
  __shared__ int seli[64][2];
  const int tid = threadIdx.x;
  const int r = tid & 63, g = tid >> 6;
  const int row = blockIdx.x * 64 + r;
  if (tid < KE) lcnt[tid] = 0;
  float lg[KE];
#pragma unroll
  for (int q = 0; q < KE; q++) lg[q] = 0.f;
#pragma unroll
  for (int s2_ = 0; s2_ < 2; s2_++) {
    const float4* a = (const float4*)(glp + ((size_t)(2 * g + s2_) * Bn + row) * KE);
#pragma unroll
    for (int u = 0; u < 4; u++) {
      float4 v = a[u];
      lg[u * 4 + 0] += v.x; lg[u * 4 + 1] += v.y;
      lg[u * 4 + 2] += v.z; lg[u * 4 + 3] += v.w;
    }
  }
#pragma unroll
  for (int q = 0; q < KE; q++) part[g][r][q] = lg[q];
  __syncthreads();

  int i1 = 0, i2 = 0, o1 = 0, o2 = 0;
  float v1 = 0.f, v2 = 0.f;
  if (tid < 64) {
#pragma unroll
    for (int q = 0; q < KE; q++)
      lg[q] = part[0][tid][q] + part[1][tid][q] + part[2][tid][q] +
              part[3][tid][q] + gb2[q];
    float m = lg[0];
#pragma unroll
    for (int q = 1; q < KE; q++) m = fmaxf(m, lg[q]);
    float e[KE];
#pragma unroll
    for (int q = 0; q < KE; q++) e[q] = expf(lg[q] - m);
    v1 = e[0];
#pragma unroll
    for (int q = 1; q < KE; q++) if (e[q] > v1) { v1 = e[q]; i1 = q; }
    i2 = (i1 == 0) ? 1 : 0; v2 = e[i2];
#pragma unroll
    for (int q = 0; q < KE; q++)
      if (q != i1 && e[q] > v2) { v2 = e[q]; i2 = q; }
    o1 = atomicAdd(&lcnt[i1], 1);
    o2 = atomicAdd(&lcnt[i2], 1);
  }
  __syncthreads();
  if (tid < KE) gbase[tid] = atomicAdd(&cnt[tid], lcnt[tid]);
  __syncthreads();
  if (tid < 64) {
    int rowg = blockIdx.x * 64 + tid;
    float den = v1 + v2;
    int s1 = gbase[i1] + o1;
    list[i1 * Bn + s1] = rowg; wlist[i1 * Bn + s1] = v1 / den;
    int s2 = gbase[i2] + o2;
    list[i2 * Bn + s2] = rowg; wlist[i2 * Bn + s2] = v2 / den;
    selk[tid][0] = i1; seli[tid][0] = s1;
    selk[tid][1] = i2; seli[tid][1] = s2;
  }
  __syncthreads();

  // pack: 128 entries x 20 fields = 2560 tasks, 10 per thread
#pragma unroll 2
  for (int it = 0; it < 10; it++) {
    int t = it * 256 + tid;
    int entry = t / NF, f = t % NF;
    int rr = entry >> 1, ch = entry & 1;
    int k = selk[rr][ch], i = seli[rr][ch];
    int rid = blockIdx.x * 64 + rr;
    int idx = x[rid * NF + f];
    const float4* s = (const float4*)(demb + (size_t)idx * NEMB);
    float4 v[4] = {s[0], s[1], s[2], s[3]};
    const float* sf = (const float*)v;
    short8 q0, q1;
#pragma unroll
    for (int e = 0; e < 8; e++) {
      q0[e] = (short)f2bf(sf[e]);
      q1[e] = (short)f2bf(sf[8 + e]);
    }
    int panel = i >> 5, mt = (i >> 4) & 1, lr = i & 15;
    int ks = f >> 1, ko0 = (f & 1) * 2;
    unsigned short* d = XEP + (size_t)k * 1310720 + (size_t)panel * 10240 +
                        ks * 1024 + mt * 512 + ko0 * 128 + lr * 8;
    *(short8*)d = q0;
    *(short8*)(d + 128) = q1;
  }
}

// ---------------- experts: ring-3 pipeline, XCD-pinned; bid 512 = loss ------
__global__ __launch_bounds__(256, 2) void expert_kernel(
    const unsigned short* __restrict__ XEP, const unsigned short* __restrict__ EWF,
    const float* __restrict__ eb1, const float* __restrict__ ew2,
    const float* __restrict__ eb2, const int* __restrict__ cnt,
    const int* __restrict__ list, const float* __restrict__ wlist,
    float* __restrict__ y) {
  __shared__ __align__(16) unsigned short ring[3][10240];  // 60 KB
  __shared__ float pb[16][4][32];                          // 8 KB
  const int tid = threadIdx.x, lane = tid & 63, wv = tid >> 6;
  const int bid = blockIdx.x;

  if (bid == 512) {  // loss block (cnt/wlist final after gate2pack)
    float (*simp)[KE] = (float(*)[KE])&pb[0][0][0];
    float* fimp = &pb[8][0][0];
    const int kk = tid >> 4, g = tid & 15;
    const int n = cnt[kk];
    float s = 0.f;
    for (int j = g; j < n; j += 16) s += wlist[kk * Bn + j];
    simp[kk][g] = s;
    __syncthreads();
    if (tid < KE) {
      float t = 0.f;
      for (int q = 0; q < KE; q++) t += simp[tid][q];
      fimp[tid] = t;
    }
    __syncthreads();
    if (tid == 0) {
      double mi = 0.0, ml = 0.0;
      for (int q = 0; q < KE; q++) { mi += fimp[q]; ml += (double)cnt[q]; }
      mi /= KE; ml /= KE;
      double vi = 0.0, vl = 0.0;
      for (int q = 0; q < KE; q++) {
        double di = fimp[q] - mi; vi += di * di;
        double dl = (double)cnt[q] - ml; vl += dl * dl;
      }
      vi /= KE; vl /= KE;
      y[Bn] = (float)(vi / (mi * mi + 1e-10) + vl / (ml * ml + 1e-10));
    }
    return;
  }

  const int xcd = bid & 7, r_ = bid >> 3;
  const int k = xcd + 8 * (r_ & 1);
  const int cb = (r_ >> 1) & 3, qz = r_ >> 3;
  const int n = cnt[k];
  const int np = (n + 31) >> 5;
  const int npb = (np > qz) ? ((np - qz + 7) >> 3) : 0;
  if (npb == 0) return;
  const unsigned short* XEPk = XEP + (size_t)k * 1310720;
  const int kBn = k * Bn;

  float b1v[2], w2v[2];
#pragma unroll
  for (int nt = 0; nt < 2; nt++) {
    int colg = cb * 128 + (wv * 2 + nt) * 16 + (lane & 15);
    b1v[nt] = eb1[(size_t)k * HIDN + colg];
    w2v[nt] = ew2[(size_t)k * HIDN + colg];
  }
  short8 bb[2][NKS];
#pragma unroll
  for (int nt = 0; nt < 2; nt++)
#pragma unroll
    for (int ks = 0; ks < NKS; ks++)
      bb[nt][ks] = *(const short8*)(
          EWF + ((size_t)((k * NKS + ks) * 32 + cb * 8 + wv * 2 + nt)) * 512 +
          lane * 8);
  __builtin_amdgcn_sched_barrier(0);

#define ESTG(pi, slot)                                                        \
  {                                                                           \
    _Pragma("unroll") for (int i = 0; i < 5; i++) {                           \
      int c = wv * 5 + i;                                                     \
      gload_lds16(XEPk + (size_t)(pi) * 10240 + c * 512 + lane * 8,           \
                  &ring[slot][c * 512 + lane * 8]);                           \
    }                                                                         \
  }

  ESTG(qz, 0)
  if (npb > 1) ESTG(qz + 8, 1)
  __builtin_amdgcn_sched_barrier(0);

  for (int p = 0; p < npb; p++) {
    vwait((p + 1 < npb) ? 5 : 0);
    __builtin_amdgcn_s_barrier();
    __builtin_amdgcn_sched_barrier(0);
    if (p + 2 < npb) ESTG(qz + 8 * (p + 2), (p + 2) % 3)
    __builtin_amdgcn_sched_barrier(0);
    const unsigned short* rb = ring[p % 3];
    f32x4 acc[2][2] = {};
#pragma unroll
    for (int ks = 0; ks < NKS; ks++) {
      short8 a0 = *(const short8*)&rb[ks * 1024 + lane * 8];
      short8 a1 = *(const short8*)&rb[ks * 1024 + 512 + lane * 8];
      acc[0][0] = __builtin_amdgcn_mfma_f32_16x16x32_bf16(a0, bb[0][ks], acc[0][0], 0, 0, 0);
      acc[0][1] = __builtin_amdgcn_mfma_f32_16x16x32_bf16(a0, bb[1][ks], acc[0][1], 0, 0, 0);
      acc[1][0] = __builtin_amdgcn_mfma_f32_16x16x32_bf16(a1, bb[0][ks], acc[1][0], 0, 0, 0);
      acc[1][1] = __builtin_amdgcn_mfma_f32_16x16x32_bf16(a1, bb[1][ks], acc[1][1], 0, 0, 0);
    }
    float part[2][4];
#pragma unroll
    for (int mt = 0; mt < 2; mt++)
#pragma unroll
      for (int j = 0; j < 4; j++)
        part[mt][j] = fmaxf(acc[mt][0][j] + b1v[0], 0.f) * w2v[0] +
                      fmaxf(acc[mt][1][j] + b1v[1], 0.f) * w2v[1];
#pragma unroll
    for (int off = 8; off >= 1; off >>= 1)
#pragma unroll
      for (int mt = 0; mt < 2; mt++)
#pragma unroll
        for (int j = 0; j < 4; j++)
          part[mt][j] += __shfl_xor(part[mt][j], off);
    if ((lane & 15) == 0) {
#pragma unroll
      for (int mt = 0; mt < 2; mt++)
#pragma unroll
        for (int j = 0; j < 4; j++)
          pb[p][wv][mt * 16 + (lane >> 4) * 4 + j] = part[mt][j];
    }
  }
  __syncthreads();

  const float e2 = (cb == 0) ? eb2[k] : 0.f;
  for (int t = tid; t < npb * 32; t += 256) {
    int pp = t >> 5, r = t & 31;
    int i = (qz + 8 * pp) * 32 + r;
    if (i < n) {
      float v = pb[pp][0][r] + pb[pp][1][r] + pb[pp][2][r] + pb[pp][3][r];
      atomicAdd(&y[list[kBn + i]], wlist[kBn + i] * (v + e2));
    }
  }
#undef ESTG
}

extern "C" void kernel_launch(void* const* d_in, const int* in_sizes, int n_in,
                              void* d_out, int out_size, void* d_ws, size_t ws_size,
                              hipStream_t stream) {
  const int* x      = (const int*)d_in[0];
  const int* sql    = (const int*)d_in[1];
  const float* semb = (const float*)d_in[2];
  const float* demb = (const float*)d_in[3];
  const float* gw1  = (const float*)d_in[4];
  const float* gb1  = (const float*)d_in[5];
  const float* gw2  = (const float*)d_in[6];
  const float* gb2  = (const float*)d_in[7];
  const float* ew1  = (const float*)d_in[8];
  const float* eb1  = (const float*)d_in[9];
  const float* ew2  = (const float*)d_in[10];
  const float* eb2  = (const float*)d_in[11];
  float* y = (float*)d_out;

  char* ws = (char*)d_ws;
  int* cnt            = (int*)(ws);                        // 64 B
  int* list           = (int*)(ws + 4096);                 // 256 KB
  float* wlist        = (float*)(ws + 266240);             // 256 KB
  float* glp          = (float*)(ws + 528384);             // 2 MB (8 slices)
  unsigned short* SH  = (unsigned short*)(ws + 5246976);   // 2.62 MB
  unsigned short* SL  = (unsigned short*)(ws + 7868416);   // 2.62 MB
  unsigned short* GWF = (unsigned short*)(ws + 10489856);  // 655 KB
  unsigned short* EWF = (unsigned short*)(ws + 11145216);  // 5.24 MB
  unsigned short* XEP = (unsigned short*)(ws + 16777216);  // 42 MB packed A

  prep_kernel<<<1777, 256, 0, stream>>>(sql, semb, gw1, ew1,
                                        SH, SL, GWF, EWF, y, cnt);
  gate_kernel<<<512, 256, 0, stream>>>(SH, SL, GWF, gb1, gw2, glp);
  gate2pack_kernel<<<64, 256, 0, stream>>>(glp, gb2, x, demb,
                                           cnt, list, wlist, XEP);
  expert_kernel<<<513, 256, 0, stream>>>(XEP, EWF, eb1, ew2, eb2,
                                         cnt, list, wlist, y);
}